// Round 5
// baseline (155.129 us; speedup 1.0000x reference)
//
#include <hip/hip_runtime.h>
#include <hip/hip_bf16.h>

#define LSEQ 20000
#define DEG  16
#define F    128
#define ALPHA 0.2f

typedef __bf16 bf16x8 __attribute__((ext_vector_type(8)));
typedef float  f32x4  __attribute__((ext_vector_type(4)));

// Prep: wt[n*F+k] = bf16(W[k*F+n]) (32 KB, cache-resident in gemm) and
// wa[k] = (W @ a1)[k], wa[F+k] = (W @ a2)[k] (fp32, for the s1/s2 path).
__global__ __launch_bounds__(256) void gat_wt(const float* __restrict__ W,
                                              const float* __restrict__ a,
                                              __hip_bfloat16* __restrict__ wt,
                                              float* __restrict__ wa)
{
    const int t = blockIdx.x * 256 + threadIdx.x;
    for (int i = t; i < F * F; i += 16 * 256) {
        const int k = i >> 7, n = i & (F - 1);
        wt[n * F + k] = __float2bfloat16(W[i]);
    }
    if (blockIdx.x == 0 && threadIdx.x < F) {
        const int k = threadIdx.x;
        float acc1 = 0.f, acc2 = 0.f;
        for (int n = 0; n < F; ++n) {
            const float w = W[k * F + n];
            acc1 = fmaf(w, a[n],     acc1);
            acc2 = fmaf(w, a[F + n], acc2);
        }
        wa[k]     = acc1;
        wa[F + k] = acc2;
    }
}

// MFMA gemm, transposed operand roles: D = wt-frag (A) x x^T-frag (B), so
// lane (q=lane>>4, m=lane&15) holds y[i0+m][ct*16 + q*4 + r], r=0..3 ->
// 4 CONSECUTIVE y columns -> one 8B dwordx2 store per ct (vs 32x 2B before).
// s1/s2 computed from the fp32 x chunks against wa1/wa2 (no y dependency).
// 16 rows/wave, 5000 waves for latency hiding.
__global__ __launch_bounds__(256) void gat_gemm(const float* __restrict__ x,
                                                const __hip_bfloat16* __restrict__ wt,
                                                const float* __restrict__ wa,
                                                __hip_bfloat16* __restrict__ y16,
                                                float* __restrict__ s1,
                                                float* __restrict__ s2)
{
    const int lane = threadIdx.x & 63;
    const int wv   = (blockIdx.x * 256 + threadIdx.x) >> 6;  // global wave id
    const int i0   = wv * 16;                                // 16 x-rows/wave
    const int m    = lane & 15;
    const int q    = lane >> 4;

    // fp32 x chunks: lane holds x[i0+m][q*8 + kt*32 + j], j=0..7, kt=0..3.
    const float* xr = x + (size_t)(i0 + m) * F + q * 8;
    float4 xf[8];
    #pragma unroll
    for (int kt = 0; kt < 4; ++kt) {
        xf[2*kt]   = *reinterpret_cast<const float4*>(xr + kt * 32);
        xf[2*kt+1] = *reinterpret_cast<const float4*>(xr + kt * 32 + 4);
    }

    // s1/s2: fp32 dot with wa1/wa2 over this lane's 32 k's, reduce over q.
    float p1 = 0.f, p2 = 0.f;
    {
        const float* w1p = wa + q * 8;
        const float* w2p = wa + F + q * 8;
        #pragma unroll
        for (int kt = 0; kt < 4; ++kt) {
            const float4 u0 = *reinterpret_cast<const float4*>(w1p + kt * 32);
            const float4 u1 = *reinterpret_cast<const float4*>(w1p + kt * 32 + 4);
            const float4 v0 = *reinterpret_cast<const float4*>(w2p + kt * 32);
            const float4 v1 = *reinterpret_cast<const float4*>(w2p + kt * 32 + 4);
            const float4 xa = xf[2*kt], xb = xf[2*kt+1];
            p1 = fmaf(xa.x,u0.x,p1); p1 = fmaf(xa.y,u0.y,p1);
            p1 = fmaf(xa.z,u0.z,p1); p1 = fmaf(xa.w,u0.w,p1);
            p1 = fmaf(xb.x,u1.x,p1); p1 = fmaf(xb.y,u1.y,p1);
            p1 = fmaf(xb.z,u1.z,p1); p1 = fmaf(xb.w,u1.w,p1);
            p2 = fmaf(xa.x,v0.x,p2); p2 = fmaf(xa.y,v0.y,p2);
            p2 = fmaf(xa.z,v0.z,p2); p2 = fmaf(xa.w,v0.w,p2);
            p2 = fmaf(xb.x,v1.x,p2); p2 = fmaf(xb.y,v1.y,p2);
            p2 = fmaf(xb.z,v1.z,p2); p2 = fmaf(xb.w,v1.w,p2);
        }
    }
    p1 += __shfl_xor(p1, 16); p1 += __shfl_xor(p1, 32);
    p2 += __shfl_xor(p2, 16); p2 += __shfl_xor(p2, 32);
    if (lane < 16) {
        s1[i0 + m] = p1;
        s2[i0 + m] = p2;
    }

    // B-fragments (x^T): B[k=q*8+j][n=m] = x[i0+m][k].
    bf16x8 bfr[4];
    #pragma unroll
    for (int kt = 0; kt < 4; ++kt) {
        const float4 qa = xf[2*kt], qb = xf[2*kt+1];
        bf16x8 f;
        f[0] = (__bf16)qa.x; f[1] = (__bf16)qa.y; f[2] = (__bf16)qa.z; f[3] = (__bf16)qa.w;
        f[4] = (__bf16)qb.x; f[5] = (__bf16)qb.y; f[6] = (__bf16)qb.z; f[7] = (__bf16)qb.w;
        bfr[kt] = f;
    }

    // ct loop over 8 column tiles. A-frag: A[mm=m][k=q*8+j] = wt[ct*16+mm][k].
    #pragma unroll
    for (int ct = 0; ct < 8; ++ct) {
        union { uint4 u; bf16x8 v; } afr[4];
        const __hip_bfloat16* wrow = wt + (size_t)(ct * 16 + m) * F + q * 8;
        #pragma unroll
        for (int kt = 0; kt < 4; ++kt)
            afr[kt].u = *reinterpret_cast<const uint4*>(wrow + kt * 32);

        f32x4 acc = {0.f, 0.f, 0.f, 0.f};
        #pragma unroll
        for (int kt = 0; kt < 4; ++kt)
            acc = __builtin_amdgcn_mfma_f32_16x16x32_bf16(afr[kt].v, bfr[kt], acc, 0, 0, 0);

        // lane holds y[i0+m][ct*16 + q*4 + r], r=0..3 -> contiguous 8B.
        union { uint2 u; __hip_bfloat162 h[2]; } pk;
        pk.h[0] = __float22bfloat162_rn(make_float2(acc[0], acc[1]));
        pk.h[1] = __float22bfloat162_rn(make_float2(acc[2], acc[3]));
        *reinterpret_cast<uint2*>(y16 + (size_t)(i0 + m) * F + ct * 16 + q * 4) = pk.u;
    }
}

// Kernel 2: one wave per (b,l). e_d = s1[adj_d] + s2[adj_0]; softmax over
// leaky_relu(e); out = elu(sum_d attn_d * y16[adj_d]). Lane holds 2 columns.
// Gathers batched with readlane->SGPR addressing: 16 loads in flight.
__global__ __launch_bounds__(256) void gat_attn(const int* __restrict__ adj,
                                                const __hip_bfloat16* __restrict__ y16,
                                                const float* __restrict__ s1,
                                                const float* __restrict__ s2,
                                                float* __restrict__ out)
{
    const int lane = threadIdx.x & 63;
    const int wid  = threadIdx.x >> 6;
    const int gl   = blockIdx.x * 4 + wid;      // flat (b,l)
    const int b    = gl / LSEQ;
    const int base = b * LSEQ;

    const int* adjp = adj + (size_t)gl * DEG;
    int av = (lane < DEG) ? adjp[lane] : 0;

    float sv = (lane < DEG) ? s1[base + av] : 0.f;
    const int a0 = __builtin_amdgcn_readlane(av, 0);
    const float e = sv + s2[base + a0];
    const float t = e > 0.f ? e : ALPHA * e;

    // softmax over lanes 0..15 (shuffles stay inside the 16-lane group)
    float m = t;
    #pragma unroll
    for (int off = 8; off; off >>= 1) m = fmaxf(m, __shfl_xor(m, off));
    float w = (lane < DEG) ? __expf(t - m) : 0.f;
    float p = w;
    #pragma unroll
    for (int off = 8; off; off >>= 1) p += __shfl_xor(p, off);
    const float attn = w / p;   // valid on lanes 0..15 (only those are read)

    // Batched gather: scalar (SGPR) row bases, 16 loads outstanding.
    unsigned int v[DEG];
    #pragma unroll
    for (int d = 0; d < DEG; ++d) {
        const int nb = __builtin_amdgcn_readlane(av, d);          // uniform
        const unsigned int* row =
            reinterpret_cast<const unsigned int*>(y16 + ((size_t)(base + nb) << 7));
        v[d] = row[lane];
    }

    float accx = 0.f, accy = 0.f;
    #pragma unroll
    for (int d = 0; d < DEG; ++d) {
        const float ad = __uint_as_float(
            __builtin_amdgcn_readlane(__float_as_uint(attn), d));  // uniform
        accx = fmaf(ad, __uint_as_float(v[d] << 16),          accx);
        accy = fmaf(ad, __uint_as_float(v[d] & 0xffff0000u),  accy);
    }
    const float ox = accx > 0.f ? accx : __expf(accx) - 1.f;
    const float oy = accy > 0.f ? accy : __expf(accy) - 1.f;
    *reinterpret_cast<float2*>(out + (size_t)gl * F + lane * 2) = make_float2(ox, oy);
}

extern "C" void kernel_launch(void* const* d_in, const int* in_sizes, int n_in,
                              void* d_out, int out_size, void* d_ws, size_t ws_size,
                              hipStream_t stream) {
    const float* x   = (const float*)d_in[0];
    const int*   adj = (const int*)d_in[1];
    const float* W   = (const float*)d_in[2];
    const float* a   = (const float*)d_in[3];
    float* out = (float*)d_out;

    const int BL = in_sizes[0] / F;   // bs*L = 80000

    __hip_bfloat16* y16 = (__hip_bfloat16*)d_ws;
    float* s1 = (float*)((char*)d_ws + (size_t)BL * F * sizeof(__hip_bfloat16));
    float* s2 = s1 + BL;
    __hip_bfloat16* wt = (__hip_bfloat16*)(s2 + BL);
    float* wa = (float*)(wt + F * F);

    gat_wt  <<<16, 256, 0, stream>>>(W, a, wt, wa);
    gat_gemm<<<BL / 64, 256, 0, stream>>>(x, wt, wa, y16, s1, s2);
    gat_attn<<<BL / 4, 256, 0, stream>>>(adj, y16, s1, s2, out);
}

// Round 6
// 150.742 us; speedup vs baseline: 1.0291x; 1.0291x over previous
//
#include <hip/hip_runtime.h>
#include <hip/hip_bf16.h>

#define LSEQ 20000
#define DEG  16
#define F    128
#define ALPHA 0.2f

typedef __bf16 bf16x8 __attribute__((ext_vector_type(8)));
typedef float  f32x4  __attribute__((ext_vector_type(4)));

// Prep: wt[n*F+k] = bf16(W[k*F+n]) (32 KB, cache-resident in gemm) and
// wa[k] = (W @ a1)[k], wa[F+k] = (W @ a2)[k] (fp32, for the s1/s2 path).
__global__ __launch_bounds__(256) void gat_wt(const float* __restrict__ W,
                                              const float* __restrict__ a,
                                              __hip_bfloat16* __restrict__ wt,
                                              float* __restrict__ wa)
{
    const int t = blockIdx.x * 256 + threadIdx.x;
    for (int i = t; i < F * F; i += 16 * 256) {
        const int k = i >> 7, n = i & (F - 1);
        wt[n * F + k] = __float2bfloat16(W[i]);
    }
    if (blockIdx.x == 0 && threadIdx.x < F) {
        const int k = threadIdx.x;
        float acc1 = 0.f, acc2 = 0.f;
        for (int n = 0; n < F; ++n) {
            const float w = W[k * F + n];
            acc1 = fmaf(w, a[n],     acc1);
            acc2 = fmaf(w, a[F + n], acc2);
        }
        wa[k]     = acc1;
        wa[F + k] = acc2;
    }
}

// MFMA gemm, transposed operand roles: D = wt-frag (A) x x^T-frag (B), so
// lane (q=lane>>4, m=lane&15) holds y[i0+m][ct*16 + q*4 + r], r=0..3 ->
// 4 CONSECUTIVE y columns -> one 8B dwordx2 store per ct.
// s1/s2 computed from the fp32 x chunks against wa1/wa2 (no y dependency).
// 16 rows/wave, 5000 waves.
__global__ __launch_bounds__(256) void gat_gemm(const float* __restrict__ x,
                                                const __hip_bfloat16* __restrict__ wt,
                                                const float* __restrict__ wa,
                                                __hip_bfloat16* __restrict__ y16,
                                                float* __restrict__ s1,
                                                float* __restrict__ s2)
{
    const int lane = threadIdx.x & 63;
    const int wv   = (blockIdx.x * 256 + threadIdx.x) >> 6;  // global wave id
    const int i0   = wv * 16;                                // 16 x-rows/wave
    const int m    = lane & 15;
    const int q    = lane >> 4;

    // fp32 x chunks: lane holds x[i0+m][q*8 + kt*32 + j], j=0..7, kt=0..3.
    const float* xr = x + (size_t)(i0 + m) * F + q * 8;
    float4 xf[8];
    #pragma unroll
    for (int kt = 0; kt < 4; ++kt) {
        xf[2*kt]   = *reinterpret_cast<const float4*>(xr + kt * 32);
        xf[2*kt+1] = *reinterpret_cast<const float4*>(xr + kt * 32 + 4);
    }

    // s1/s2: fp32 dot with wa1/wa2 over this lane's 32 k's, reduce over q.
    float p1 = 0.f, p2 = 0.f;
    {
        const float* w1p = wa + q * 8;
        const float* w2p = wa + F + q * 8;
        #pragma unroll
        for (int kt = 0; kt < 4; ++kt) {
            const float4 u0 = *reinterpret_cast<const float4*>(w1p + kt * 32);
            const float4 u1 = *reinterpret_cast<const float4*>(w1p + kt * 32 + 4);
            const float4 v0 = *reinterpret_cast<const float4*>(w2p + kt * 32);
            const float4 v1 = *reinterpret_cast<const float4*>(w2p + kt * 32 + 4);
            const float4 xa = xf[2*kt], xb = xf[2*kt+1];
            p1 = fmaf(xa.x,u0.x,p1); p1 = fmaf(xa.y,u0.y,p1);
            p1 = fmaf(xa.z,u0.z,p1); p1 = fmaf(xa.w,u0.w,p1);
            p1 = fmaf(xb.x,u1.x,p1); p1 = fmaf(xb.y,u1.y,p1);
            p1 = fmaf(xb.z,u1.z,p1); p1 = fmaf(xb.w,u1.w,p1);
            p2 = fmaf(xa.x,v0.x,p2); p2 = fmaf(xa.y,v0.y,p2);
            p2 = fmaf(xa.z,v0.z,p2); p2 = fmaf(xa.w,v0.w,p2);
            p2 = fmaf(xb.x,v1.x,p2); p2 = fmaf(xb.y,v1.y,p2);
            p2 = fmaf(xb.z,v1.z,p2); p2 = fmaf(xb.w,v1.w,p2);
        }
    }
    p1 += __shfl_xor(p1, 16); p1 += __shfl_xor(p1, 32);
    p2 += __shfl_xor(p2, 16); p2 += __shfl_xor(p2, 32);
    if (lane < 16) {
        s1[i0 + m] = p1;
        s2[i0 + m] = p2;
    }

    // B-fragments (x^T): B[k=q*8+j][n=m] = x[i0+m][k].
    bf16x8 bfr[4];
    #pragma unroll
    for (int kt = 0; kt < 4; ++kt) {
        const float4 qa = xf[2*kt], qb = xf[2*kt+1];
        bf16x8 f;
        f[0] = (__bf16)qa.x; f[1] = (__bf16)qa.y; f[2] = (__bf16)qa.z; f[3] = (__bf16)qa.w;
        f[4] = (__bf16)qb.x; f[5] = (__bf16)qb.y; f[6] = (__bf16)qb.z; f[7] = (__bf16)qb.w;
        bfr[kt] = f;
    }

    // ct loop over 8 column tiles. A-frag: A[mm=m][k=q*8+j] = wt[ct*16+mm][k].
    #pragma unroll
    for (int ct = 0; ct < 8; ++ct) {
        union { uint4 u; bf16x8 v; } afr[4];
        const __hip_bfloat16* wrow = wt + (size_t)(ct * 16 + m) * F + q * 8;
        #pragma unroll
        for (int kt = 0; kt < 4; ++kt)
            afr[kt].u = *reinterpret_cast<const uint4*>(wrow + kt * 32);

        f32x4 acc = {0.f, 0.f, 0.f, 0.f};
        #pragma unroll
        for (int kt = 0; kt < 4; ++kt)
            acc = __builtin_amdgcn_mfma_f32_16x16x32_bf16(afr[kt].v, bfr[kt], acc, 0, 0, 0);

        // lane holds y[i0+m][ct*16 + q*4 + r], r=0..3 -> contiguous 8B.
        union { uint2 u; __hip_bfloat162 h[2]; } pk;
        pk.h[0] = __float22bfloat162_rn(make_float2(acc[0], acc[1]));
        pk.h[1] = __float22bfloat162_rn(make_float2(acc[2], acc[3]));
        *reinterpret_cast<uint2*>(y16 + (size_t)(i0 + m) * F + ct * 16 + q * 4) = pk.u;
    }
}

// Kernel 2: one wave per (b,l). e_d = s1[adj_d] + s2[adj_0]; softmax over
// leaky_relu(e); out = elu(sum_d attn_d * y16[adj_d]). Lane holds 2 columns.
// XCD-aware swizzle: dispatch round-robins block i -> XCD i%8 (m09). Pin
// XCD pair {2b,2b+1} to batch b so the batch's 5.1 MB y16 gather window
// stays resident in the pair's 8 MB of L2 (default mapping thrashes all 4
// windows = 20.5 MB through every 4 MB XCD L2 -> 4x HBM refetch, R3:
// FETCH 85.7 MB vs 26 ideal).
__global__ __launch_bounds__(256) void gat_attn(const int* __restrict__ adj,
                                                const __hip_bfloat16* __restrict__ y16,
                                                const float* __restrict__ s1,
                                                const float* __restrict__ s2,
                                                float* __restrict__ out)
{
    const int lane  = threadIdx.x & 63;
    const int wid   = threadIdx.x >> 6;
    const int x8    = blockIdx.x & 7;
    const int j     = blockIdx.x >> 3;          // 0..2499
    const int batch = x8 >> 1;                  // XCD pair -> batch
    const int nb    = j * 2 + (x8 & 1);         // 0..4999 within batch
    const int gl    = batch * LSEQ + nb * 4 + wid;
    const int base  = batch * LSEQ;

    const int* adjp = adj + (size_t)gl * DEG;
    int av = (lane < DEG) ? adjp[lane] : 0;

    float sv = (lane < DEG) ? s1[base + av] : 0.f;
    const int a0 = __builtin_amdgcn_readlane(av, 0);
    const float e = sv + s2[base + a0];
    const float t = e > 0.f ? e : ALPHA * e;

    // softmax over lanes 0..15 (shuffles stay inside the 16-lane group)
    float m = t;
    #pragma unroll
    for (int off = 8; off; off >>= 1) m = fmaxf(m, __shfl_xor(m, off));
    float w = (lane < DEG) ? __expf(t - m) : 0.f;
    float p = w;
    #pragma unroll
    for (int off = 8; off; off >>= 1) p += __shfl_xor(p, off);
    const float attn = w / p;   // valid on lanes 0..15 (only those are read)

    // Batched gather: scalar (SGPR) row bases, 16 loads outstanding.
    unsigned int v[DEG];
    #pragma unroll
    for (int d = 0; d < DEG; ++d) {
        const int nbr = __builtin_amdgcn_readlane(av, d);         // uniform
        const unsigned int* row =
            reinterpret_cast<const unsigned int*>(y16 + ((size_t)(base + nbr) << 7));
        v[d] = row[lane];
    }

    float accx = 0.f, accy = 0.f;
    #pragma unroll
    for (int d = 0; d < DEG; ++d) {
        const float ad = __uint_as_float(
            __builtin_amdgcn_readlane(__float_as_uint(attn), d));  // uniform
        accx = fmaf(ad, __uint_as_float(v[d] << 16),          accx);
        accy = fmaf(ad, __uint_as_float(v[d] & 0xffff0000u),  accy);
    }
    const float ox = accx > 0.f ? accx : __expf(accx) - 1.f;
    const float oy = accy > 0.f ? accy : __expf(accy) - 1.f;
    *reinterpret_cast<float2*>(out + (size_t)gl * F + lane * 2) = make_float2(ox, oy);
}

extern "C" void kernel_launch(void* const* d_in, const int* in_sizes, int n_in,
                              void* d_out, int out_size, void* d_ws, size_t ws_size,
                              hipStream_t stream) {
    const float* x   = (const float*)d_in[0];
    const int*   adj = (const int*)d_in[1];
    const float* W   = (const float*)d_in[2];
    const float* a   = (const float*)d_in[3];
    float* out = (float*)d_out;

    const int BL = in_sizes[0] / F;   // bs*L = 80000

    __hip_bfloat16* y16 = (__hip_bfloat16*)d_ws;
    float* s1 = (float*)((char*)d_ws + (size_t)BL * F * sizeof(__hip_bfloat16));
    float* s2 = s1 + BL;
    __hip_bfloat16* wt = (__hip_bfloat16*)(s2 + BL);
    float* wa = (float*)(wt + F * F);

    gat_wt  <<<16, 256, 0, stream>>>(W, a, wt, wa);
    gat_gemm<<<BL / 64, 256, 0, stream>>>(x, wt, wa, y16, s1, s2);
    gat_attn<<<BL / 4, 256, 0, stream>>>(adj, y16, s1, s2, out);
}

// Round 7
// 148.619 us; speedup vs baseline: 1.0438x; 1.0143x over previous
//
#include <hip/hip_runtime.h>
#include <hip/hip_bf16.h>

#define LSEQ 20000
#define DEG  16
#define F    128
#define ALPHA 0.2f

typedef __bf16 bf16x8 __attribute__((ext_vector_type(8)));
typedef float  f32x4  __attribute__((ext_vector_type(4)));

// Prep: wt[n*F+k] = bf16(W[k*F+n]) (32 KB, cache-resident in gemm) and
// wa[k] = (W @ a1)[k], wa[F+k] = (W @ a2)[k] (fp32, for the s1/s2 path).
__global__ __launch_bounds__(256) void gat_wt(const float* __restrict__ W,
                                              const float* __restrict__ a,
                                              __hip_bfloat16* __restrict__ wt,
                                              float* __restrict__ wa)
{
    const int t = blockIdx.x * 256 + threadIdx.x;
    for (int i = t; i < F * F; i += 16 * 256) {
        const int k = i >> 7, n = i & (F - 1);
        wt[n * F + k] = __float2bfloat16(W[i]);
    }
    if (blockIdx.x == 0 && threadIdx.x < F) {
        const int k = threadIdx.x;
        float acc1 = 0.f, acc2 = 0.f;
        for (int n = 0; n < F; ++n) {
            const float w = W[k * F + n];
            acc1 = fmaf(w, a[n],     acc1);
            acc2 = fmaf(w, a[F + n], acc2);
        }
        wa[k]     = acc1;
        wa[F + k] = acc2;
    }
}

// MFMA gemm, transposed operand roles: D = wt-frag (A) x x^T-frag (B);
// lane (q=lane>>4, m=lane&15) holds y[i0+m][ct*16 + q*4 + r] -> contiguous
// 8B stores. s1/s2 from fp32 x against wa1/wa2. 16 rows/wave, 5000 waves.
// Estimated near its 62MB/6.3TBps ~10-12us memory floor.
__global__ __launch_bounds__(256) void gat_gemm(const float* __restrict__ x,
                                                const __hip_bfloat16* __restrict__ wt,
                                                const float* __restrict__ wa,
                                                __hip_bfloat16* __restrict__ y16,
                                                float* __restrict__ s1,
                                                float* __restrict__ s2)
{
    const int lane = threadIdx.x & 63;
    const int wv   = (blockIdx.x * 256 + threadIdx.x) >> 6;  // global wave id
    const int i0   = wv * 16;                                // 16 x-rows/wave
    const int m    = lane & 15;
    const int q    = lane >> 4;

    // fp32 x chunks: lane holds x[i0+m][q*8 + kt*32 + j], j=0..7, kt=0..3.
    const float* xr = x + (size_t)(i0 + m) * F + q * 8;
    float4 xf[8];
    #pragma unroll
    for (int kt = 0; kt < 4; ++kt) {
        xf[2*kt]   = *reinterpret_cast<const float4*>(xr + kt * 32);
        xf[2*kt+1] = *reinterpret_cast<const float4*>(xr + kt * 32 + 4);
    }

    // s1/s2: fp32 dot with wa1/wa2 over this lane's 32 k's, reduce over q.
    float p1 = 0.f, p2 = 0.f;
    {
        const float* w1p = wa + q * 8;
        const float* w2p = wa + F + q * 8;
        #pragma unroll
        for (int kt = 0; kt < 4; ++kt) {
            const float4 u0 = *reinterpret_cast<const float4*>(w1p + kt * 32);
            const float4 u1 = *reinterpret_cast<const float4*>(w1p + kt * 32 + 4);
            const float4 v0 = *reinterpret_cast<const float4*>(w2p + kt * 32);
            const float4 v1 = *reinterpret_cast<const float4*>(w2p + kt * 32 + 4);
            const float4 xa = xf[2*kt], xb = xf[2*kt+1];
            p1 = fmaf(xa.x,u0.x,p1); p1 = fmaf(xa.y,u0.y,p1);
            p1 = fmaf(xa.z,u0.z,p1); p1 = fmaf(xa.w,u0.w,p1);
            p1 = fmaf(xb.x,u1.x,p1); p1 = fmaf(xb.y,u1.y,p1);
            p1 = fmaf(xb.z,u1.z,p1); p1 = fmaf(xb.w,u1.w,p1);
            p2 = fmaf(xa.x,v0.x,p2); p2 = fmaf(xa.y,v0.y,p2);
            p2 = fmaf(xa.z,v0.z,p2); p2 = fmaf(xa.w,v0.w,p2);
            p2 = fmaf(xb.x,v1.x,p2); p2 = fmaf(xb.y,v1.y,p2);
            p2 = fmaf(xb.z,v1.z,p2); p2 = fmaf(xb.w,v1.w,p2);
        }
    }
    p1 += __shfl_xor(p1, 16); p1 += __shfl_xor(p1, 32);
    p2 += __shfl_xor(p2, 16); p2 += __shfl_xor(p2, 32);
    if (lane < 16) {
        s1[i0 + m] = p1;
        s2[i0 + m] = p2;
    }

    // B-fragments (x^T): B[k=q*8+j][n=m] = x[i0+m][k].
    bf16x8 bfr[4];
    #pragma unroll
    for (int kt = 0; kt < 4; ++kt) {
        const float4 qa = xf[2*kt], qb = xf[2*kt+1];
        bf16x8 f;
        f[0] = (__bf16)qa.x; f[1] = (__bf16)qa.y; f[2] = (__bf16)qa.z; f[3] = (__bf16)qa.w;
        f[4] = (__bf16)qb.x; f[5] = (__bf16)qb.y; f[6] = (__bf16)qb.z; f[7] = (__bf16)qb.w;
        bfr[kt] = f;
    }

    // ct loop over 8 column tiles. A-frag: A[mm=m][k=q*8+j] = wt[ct*16+mm][k].
    #pragma unroll
    for (int ct = 0; ct < 8; ++ct) {
        union { uint4 u; bf16x8 v; } afr[4];
        const __hip_bfloat16* wrow = wt + (size_t)(ct * 16 + m) * F + q * 8;
        #pragma unroll
        for (int kt = 0; kt < 4; ++kt)
            afr[kt].u = *reinterpret_cast<const uint4*>(wrow + kt * 32);

        f32x4 acc = {0.f, 0.f, 0.f, 0.f};
        #pragma unroll
        for (int kt = 0; kt < 4; ++kt)
            acc = __builtin_amdgcn_mfma_f32_16x16x32_bf16(afr[kt].v, bfr[kt], acc, 0, 0, 0);

        union { uint2 u; __hip_bfloat162 h[2]; } pk;
        pk.h[0] = __float22bfloat162_rn(make_float2(acc[0], acc[1]));
        pk.h[1] = __float22bfloat162_rn(make_float2(acc[2], acc[3]));
        *reinterpret_cast<uint2*>(y16 + (size_t)(i0 + m) * F + ct * 16 + q * 4) = pk.u;
    }
}

// Kernel 2: FOUR nodes per wave (lane = node*16 + d). All 64 lanes active in
// prologue: one coalesced 256B adj load, full-wave s1 gather, softmax in
// 16-lane groups. Gather phase: node pairs -> 32 row-loads in flight.
// XCD-pair <-> batch pinning kept (5.1MB y16 window per 8MB L2 pair).
__global__ __launch_bounds__(256) void gat_attn(const int* __restrict__ adj,
                                                const __hip_bfloat16* __restrict__ y16,
                                                const float* __restrict__ s1,
                                                const float* __restrict__ s2,
                                                float* __restrict__ out)
{
    const int lane  = threadIdx.x & 63;
    const int wid   = threadIdx.x >> 6;
    const int x8    = blockIdx.x & 7;
    const int j     = blockIdx.x >> 3;          // 0..624
    const int batch = x8 >> 1;                  // XCD pair -> batch
    const int grp   = j * 2 + (x8 & 1);         // 0..1249 (16-node group)
    const int base  = batch * LSEQ;
    const int g0    = base + grp * 16 + wid * 4;   // this wave's first node

    // adj for 4 nodes: 64 contiguous ints, fully coalesced.
    const int av = adj[(size_t)g0 * DEG + lane];

    const float sv = s1[base + av];
    // s2 term: head lane (d==0) of each 16-group loads, then broadcast.
    const int d = lane & 15;
    float s2l = (d == 0) ? s2[base + av] : 0.f;
    const float s2v = __shfl(s2l, lane & 48);
    const float e = sv + s2v;
    const float t = e > 0.f ? e : ALPHA * e;

    // softmax within each 16-lane group (xor offsets stay in-group).
    float m = t;
    #pragma unroll
    for (int off = 1; off < 16; off <<= 1) m = fmaxf(m, __shfl_xor(m, off));
    const float w = __expf(t - m);
    float p = w;
    #pragma unroll
    for (int off = 1; off < 16; off <<= 1) p += __shfl_xor(p, off);
    const float attn = w / p;

    // Gather + accumulate, two nodes at a time: 32 loads outstanding.
    #pragma unroll
    for (int n = 0; n < 4; n += 2) {
        unsigned int v0[DEG], v1[DEG];
        #pragma unroll
        for (int dd = 0; dd < DEG; ++dd) {
            const int i0 = __builtin_amdgcn_readlane(av, n * 16 + dd);       // uniform
            v0[dd] = reinterpret_cast<const unsigned int*>(
                         y16 + ((size_t)(base + i0) << 7))[lane];
        }
        #pragma unroll
        for (int dd = 0; dd < DEG; ++dd) {
            const int i1 = __builtin_amdgcn_readlane(av, (n + 1) * 16 + dd); // uniform
            v1[dd] = reinterpret_cast<const unsigned int*>(
                         y16 + ((size_t)(base + i1) << 7))[lane];
        }

        float ax0 = 0.f, ay0 = 0.f, ax1 = 0.f, ay1 = 0.f;
        #pragma unroll
        for (int dd = 0; dd < DEG; ++dd) {
            const float ad0 = __uint_as_float(__builtin_amdgcn_readlane(
                                  __float_as_uint(attn), n * 16 + dd));
            union { unsigned int u; __hip_bfloat162 h; } c0; c0.u = v0[dd];
            const float2 f0 = __bfloat1622float2(c0.h);   // packed cvt
            ax0 = fmaf(ad0, f0.x, ax0); ay0 = fmaf(ad0, f0.y, ay0);

            const float ad1 = __uint_as_float(__builtin_amdgcn_readlane(
                                  __float_as_uint(attn), (n + 1) * 16 + dd));
            union { unsigned int u; __hip_bfloat162 h; } c1; c1.u = v1[dd];
            const float2 f1 = __bfloat1622float2(c1.h);
            ax1 = fmaf(ad1, f1.x, ax1); ay1 = fmaf(ad1, f1.y, ay1);
        }
        const float ox0 = ax0 > 0.f ? ax0 : __expf(ax0) - 1.f;
        const float oy0 = ay0 > 0.f ? ay0 : __expf(ay0) - 1.f;
        *reinterpret_cast<float2*>(out + (size_t)(g0 + n) * F + lane * 2)
            = make_float2(ox0, oy0);
        const float ox1 = ax1 > 0.f ? ax1 : __expf(ax1) - 1.f;
        const float oy1 = ay1 > 0.f ? ay1 : __expf(ay1) - 1.f;
        *reinterpret_cast<float2*>(out + (size_t)(g0 + n + 1) * F + lane * 2)
            = make_float2(ox1, oy1);
    }
}

extern "C" void kernel_launch(void* const* d_in, const int* in_sizes, int n_in,
                              void* d_out, int out_size, void* d_ws, size_t ws_size,
                              hipStream_t stream) {
    const float* x   = (const float*)d_in[0];
    const int*   adj = (const int*)d_in[1];
    const float* W   = (const float*)d_in[2];
    const float* a   = (const float*)d_in[3];
    float* out = (float*)d_out;

    const int BL = in_sizes[0] / F;   // bs*L = 80000

    __hip_bfloat16* y16 = (__hip_bfloat16*)d_ws;
    float* s1 = (float*)((char*)d_ws + (size_t)BL * F * sizeof(__hip_bfloat16));
    float* s2 = s1 + BL;
    __hip_bfloat16* wt = (__hip_bfloat16*)(s2 + BL);
    float* wa = (float*)(wt + F * F);

    gat_wt  <<<16, 256, 0, stream>>>(W, a, wt, wa);
    gat_gemm<<<BL / 64, 256, 0, stream>>>(x, wt, wa, y16, s1, s2);
    gat_attn<<<BL / 16, 256, 0, stream>>>(adj, y16, s1, s2, out);
}

// Round 8
// 137.023 us; speedup vs baseline: 1.1321x; 1.0846x over previous
//
#include <hip/hip_runtime.h>
#include <hip/hip_bf16.h>

#define LSEQ 20000
#define DEG  16
#define F    128
#define FP   136   // LDS row pad: +8 halfs so 16-lane stride-FP reads are 2-way (free)
#define ALPHA 0.2f

typedef __bf16 bf16x8 __attribute__((ext_vector_type(8)));
typedef float  f32x4  __attribute__((ext_vector_type(4)));

// Prep: wt[n*F+k] = bf16(W[k*F+n]) (32 KB) and wa[k] = (W@a1)[k],
// wa[F+k] = (W@a2)[k] (fp32, for the s1/s2 path).
__global__ __launch_bounds__(256) void gat_wt(const float* __restrict__ W,
                                              const float* __restrict__ a,
                                              __hip_bfloat16* __restrict__ wt,
                                              float* __restrict__ wa)
{
    const int t = blockIdx.x * 256 + threadIdx.x;
    for (int i = t; i < F * F; i += 16 * 256) {
        const int k = i >> 7, n = i & (F - 1);
        wt[n * F + k] = __float2bfloat16(W[i]);
    }
    if (blockIdx.x == 0 && threadIdx.x < F) {
        const int k = threadIdx.x;
        float acc1 = 0.f, acc2 = 0.f;
        for (int n = 0; n < F; ++n) {
            const float w = W[k * F + n];
            acc1 = fmaf(w, a[n],     acc1);
            acc2 = fmaf(w, a[F + n], acc2);
        }
        wa[k]     = acc1;
        wa[F + k] = acc2;
    }
}

// MFMA gemm. R8: wt staged in LDS once per block (one-time 32KB coalesced
// load) -> A-fragments come from ds_read_b128 instead of an 8-deep
// L2-latency chain; L2 wt traffic drops 160MB -> 40MB. Rows padded to FP=136
// halfs: fragment reads are 2-way bank-aliased (free, m136) vs 16-way
// unpadded. 34KB LDS -> 4 blocks/CU -> 16 waves/CU.
// D-layout: lane (q=lane>>4, m=lane&15) holds y[i0+m][ct*16+q*4+r] ->
// contiguous 8B stores. s1/s2 from fp32 x against wa1/wa2.
__global__ __launch_bounds__(256) void gat_gemm(const float* __restrict__ x,
                                                const __hip_bfloat16* __restrict__ wt,
                                                const float* __restrict__ wa,
                                                __hip_bfloat16* __restrict__ y16,
                                                float* __restrict__ s1,
                                                float* __restrict__ s2)
{
    __shared__ __hip_bfloat16 wl[F][FP];   // 34 KB

    const int t    = threadIdx.x;
    const int lane = t & 63;
    const int wid  = t >> 6;
    const int i0   = (blockIdx.x * 4 + wid) * 16;   // 16 x-rows per wave
    const int m    = lane & 15;
    const int q    = lane >> 4;

    // Stage wt -> LDS: 2048 uint4, 8 per thread, coalesced.
    {
        const uint4* wg = reinterpret_cast<const uint4*>(wt);
        #pragma unroll
        for (int i = 0; i < 8; ++i) {
            const int g   = t + 256 * i;       // global uint4 index
            const int row = g >> 4;            // 16 uint4 per row
            const int c8  = g & 15;            // which 8-half chunk
            *reinterpret_cast<uint4*>(&wl[row][c8 * 8]) = wg[g];
        }
    }

    // fp32 x chunks: lane holds x[i0+m][q*8 + kt*32 + j], j=0..7, kt=0..3.
    const float* xr = x + (size_t)(i0 + m) * F + q * 8;
    float4 xf[8];
    #pragma unroll
    for (int kt = 0; kt < 4; ++kt) {
        xf[2*kt]   = *reinterpret_cast<const float4*>(xr + kt * 32);
        xf[2*kt+1] = *reinterpret_cast<const float4*>(xr + kt * 32 + 4);
    }

    // s1/s2: fp32 dot with wa1/wa2 over this lane's 32 k's, reduce over q.
    float p1 = 0.f, p2 = 0.f;
    {
        const float* w1p = wa + q * 8;
        const float* w2p = wa + F + q * 8;
        #pragma unroll
        for (int kt = 0; kt < 4; ++kt) {
            const float4 u0 = *reinterpret_cast<const float4*>(w1p + kt * 32);
            const float4 u1 = *reinterpret_cast<const float4*>(w1p + kt * 32 + 4);
            const float4 v0 = *reinterpret_cast<const float4*>(w2p + kt * 32);
            const float4 v1 = *reinterpret_cast<const float4*>(w2p + kt * 32 + 4);
            const float4 xa = xf[2*kt], xb = xf[2*kt+1];
            p1 = fmaf(xa.x,u0.x,p1); p1 = fmaf(xa.y,u0.y,p1);
            p1 = fmaf(xa.z,u0.z,p1); p1 = fmaf(xa.w,u0.w,p1);
            p1 = fmaf(xb.x,u1.x,p1); p1 = fmaf(xb.y,u1.y,p1);
            p1 = fmaf(xb.z,u1.z,p1); p1 = fmaf(xb.w,u1.w,p1);
            p2 = fmaf(xa.x,v0.x,p2); p2 = fmaf(xa.y,v0.y,p2);
            p2 = fmaf(xa.z,v0.z,p2); p2 = fmaf(xa.w,v0.w,p2);
            p2 = fmaf(xb.x,v1.x,p2); p2 = fmaf(xb.y,v1.y,p2);
            p2 = fmaf(xb.z,v1.z,p2); p2 = fmaf(xb.w,v1.w,p2);
        }
    }
    p1 += __shfl_xor(p1, 16); p1 += __shfl_xor(p1, 32);
    p2 += __shfl_xor(p2, 16); p2 += __shfl_xor(p2, 32);
    if (lane < 16) {
        s1[i0 + m] = p1;
        s2[i0 + m] = p2;
    }

    // B-fragments (x^T): B[k=q*8+j][n=m] = x[i0+m][k].
    bf16x8 bfr[4];
    #pragma unroll
    for (int kt = 0; kt < 4; ++kt) {
        const float4 qa = xf[2*kt], qb = xf[2*kt+1];
        bf16x8 f;
        f[0] = (__bf16)qa.x; f[1] = (__bf16)qa.y; f[2] = (__bf16)qa.z; f[3] = (__bf16)qa.w;
        f[4] = (__bf16)qb.x; f[5] = (__bf16)qb.y; f[6] = (__bf16)qb.z; f[7] = (__bf16)qb.w;
        bfr[kt] = f;
    }

    __syncthreads();   // wt staging complete

    // ct loop over 8 column tiles; A-frag from LDS: A[mm=m][k=q*8+j].
    #pragma unroll
    for (int ct = 0; ct < 8; ++ct) {
        union { uint4 u; bf16x8 v; } afr[4];
        const __hip_bfloat16* wrow = &wl[ct * 16 + m][q * 8];
        #pragma unroll
        for (int kt = 0; kt < 4; ++kt)
            afr[kt].u = *reinterpret_cast<const uint4*>(wrow + kt * 32);

        f32x4 acc = {0.f, 0.f, 0.f, 0.f};
        #pragma unroll
        for (int kt = 0; kt < 4; ++kt)
            acc = __builtin_amdgcn_mfma_f32_16x16x32_bf16(afr[kt].v, bfr[kt], acc, 0, 0, 0);

        union { uint2 u; __hip_bfloat162 h[2]; } pk;
        pk.h[0] = __float22bfloat162_rn(make_float2(acc[0], acc[1]));
        pk.h[1] = __float22bfloat162_rn(make_float2(acc[2], acc[3]));
        *reinterpret_cast<uint2*>(y16 + (size_t)(i0 + m) * F + ct * 16 + q * 4) = pk.u;
    }
}

// Kernel 2: FOUR nodes per wave (lane = node*16 + d). One coalesced 256B adj
// load, full-wave s1 gather, softmax in 16-lane groups; gather phase runs
// node pairs -> 32 row-loads in flight. XCD-pair <-> batch pinning keeps the
// 5.1MB y16 window resident per 8MB L2 pair.
__global__ __launch_bounds__(256) void gat_attn(const int* __restrict__ adj,
                                                const __hip_bfloat16* __restrict__ y16,
                                                const float* __restrict__ s1,
                                                const float* __restrict__ s2,
                                                float* __restrict__ out)
{
    const int lane  = threadIdx.x & 63;
    const int wid   = threadIdx.x >> 6;
    const int x8    = blockIdx.x & 7;
    const int j     = blockIdx.x >> 3;          // 0..624
    const int batch = x8 >> 1;                  // XCD pair -> batch
    const int grp   = j * 2 + (x8 & 1);         // 0..1249 (16-node group)
    const int base  = batch * LSEQ;
    const int g0    = base + grp * 16 + wid * 4;   // this wave's first node

    // adj for 4 nodes: 64 contiguous ints, fully coalesced.
    const int av = adj[(size_t)g0 * DEG + lane];

    const float sv = s1[base + av];
    // s2 term: head lane (d==0) of each 16-group loads, then broadcast.
    const int d = lane & 15;
    float s2l = (d == 0) ? s2[base + av] : 0.f;
    const float s2v = __shfl(s2l, lane & 48);
    const float e = sv + s2v;
    const float t = e > 0.f ? e : ALPHA * e;

    // softmax within each 16-lane group (xor offsets stay in-group).
    float m = t;
    #pragma unroll
    for (int off = 1; off < 16; off <<= 1) m = fmaxf(m, __shfl_xor(m, off));
    const float w = __expf(t - m);
    float p = w;
    #pragma unroll
    for (int off = 1; off < 16; off <<= 1) p += __shfl_xor(p, off);
    const float attn = w / p;

    // Gather + accumulate, two nodes at a time: 32 loads outstanding.
    #pragma unroll
    for (int n = 0; n < 4; n += 2) {
        unsigned int v0[DEG], v1[DEG];
        #pragma unroll
        for (int dd = 0; dd < DEG; ++dd) {
            const int i0 = __builtin_amdgcn_readlane(av, n * 16 + dd);       // uniform
            v0[dd] = reinterpret_cast<const unsigned int*>(
                         y16 + ((size_t)(base + i0) << 7))[lane];
        }
        #pragma unroll
        for (int dd = 0; dd < DEG; ++dd) {
            const int i1 = __builtin_amdgcn_readlane(av, (n + 1) * 16 + dd); // uniform
            v1[dd] = reinterpret_cast<const unsigned int*>(
                         y16 + ((size_t)(base + i1) << 7))[lane];
        }

        float ax0 = 0.f, ay0 = 0.f, ax1 = 0.f, ay1 = 0.f;
        #pragma unroll
        for (int dd = 0; dd < DEG; ++dd) {
            const float ad0 = __uint_as_float(__builtin_amdgcn_readlane(
                                  __float_as_uint(attn), n * 16 + dd));
            union { unsigned int u; __hip_bfloat162 h; } c0; c0.u = v0[dd];
            const float2 f0 = __bfloat1622float2(c0.h);   // packed cvt
            ax0 = fmaf(ad0, f0.x, ax0); ay0 = fmaf(ad0, f0.y, ay0);

            const float ad1 = __uint_as_float(__builtin_amdgcn_readlane(
                                  __float_as_uint(attn), (n + 1) * 16 + dd));
            union { unsigned int u; __hip_bfloat162 h; } c1; c1.u = v1[dd];
            const float2 f1 = __bfloat1622float2(c1.h);
            ax1 = fmaf(ad1, f1.x, ax1); ay1 = fmaf(ad1, f1.y, ay1);
        }
        const float ox0 = ax0 > 0.f ? ax0 : __expf(ax0) - 1.f;
        const float oy0 = ay0 > 0.f ? ay0 : __expf(ay0) - 1.f;
        *reinterpret_cast<float2*>(out + (size_t)(g0 + n) * F + lane * 2)
            = make_float2(ox0, oy0);
        const float ox1 = ax1 > 0.f ? ax1 : __expf(ax1) - 1.f;
        const float oy1 = ay1 > 0.f ? ay1 : __expf(ay1) - 1.f;
        *reinterpret_cast<float2*>(out + (size_t)(g0 + n + 1) * F + lane * 2)
            = make_float2(ox1, oy1);
    }
}

extern "C" void kernel_launch(void* const* d_in, const int* in_sizes, int n_in,
                              void* d_out, int out_size, void* d_ws, size_t ws_size,
                              hipStream_t stream) {
    const float* x   = (const float*)d_in[0];
    const int*   adj = (const int*)d_in[1];
    const float* W   = (const float*)d_in[2];
    const float* a   = (const float*)d_in[3];
    float* out = (float*)d_out;

    const int BL = in_sizes[0] / F;   // bs*L = 80000

    __hip_bfloat16* y16 = (__hip_bfloat16*)d_ws;
    float* s1 = (float*)((char*)d_ws + (size_t)BL * F * sizeof(__hip_bfloat16));
    float* s2 = s1 + BL;
    __hip_bfloat16* wt = (__hip_bfloat16*)(s2 + BL);
    float* wa = (float*)(wt + F * F);

    gat_wt  <<<16, 256, 0, stream>>>(W, a, wt, wa);
    gat_gemm<<<BL / 64, 256, 0, stream>>>(x, wt, wa, y16, s1, s2);
    gat_attn<<<BL / 16, 256, 0, stream>>>(adj, y16, s1, s2, out);
}